// Round 1
// baseline (25045.627 us; speedup 1.0000x reference)
//
#include <hip/hip_runtime.h>

// Echo State Network, T=1024 sequential steps of r' = 0.5 r + 0.5 tanh(W r + Win u).
// Strategy: persistent kernel, whole 64 MB W pinned in VGPRs (256 WG x 8 waves x 2 rows,
// 128 VGPR of W per lane). Cross-WG step barrier via device-scope flags in d_ws.
// d_ws layout: [0, 32768): float rbuf[2][4096] (double-buffered r)
//              [32768, 33792): int flags[256]  (last published step per WG)

#define T_STEPS 1024
#define R_DIM   4096
#define N_WG    256
#define N_THR   512
#define ROWS_PER_WG 16
#define K_CHUNKS 16          // R_DIM / (64 lanes * 4 floats)

#define AGENT __HIP_MEMORY_SCOPE_AGENT

__global__ __launch_bounds__(N_THR, 2)
void esn_persistent(const float* __restrict__ batch,
                    const float* __restrict__ Win,
                    const float* __restrict__ W,
                    const float* __restrict__ Wout,
                    float* __restrict__ out,
                    float* __restrict__ rbuf,
                    int*   __restrict__ flags)
{
    __shared__ __align__(16) float r_lds[R_DIM];   // current r(t), broadcast to all waves
    __shared__ float b_lds[T_STEPS];               // input sequence

    const int tid  = threadIdx.x;
    const int wid  = blockIdx.x;
    const int wave = tid >> 6;
    const int lane = tid & 63;
    const int r0   = wid * ROWS_PER_WG;
    const int rowA = r0 + wave * 2;                // this wave's two W rows
    const int rowB = rowA + 1;

    for (int i = tid; i < R_DIM; i += N_THR) r_lds[i] = 0.0f;   // r(0) = 0
    for (int i = tid; i < T_STEPS; i += N_THR) b_lds[i] = batch[i];

    // Pin W rows in registers: lane holds float4 slice c at k = c*256 + lane*4.
    float4 wA[K_CHUNKS], wB[K_CHUNKS];
    {
        const float4* pA = reinterpret_cast<const float4*>(W + (size_t)rowA * R_DIM);
        const float4* pB = reinterpret_cast<const float4*>(W + (size_t)rowB * R_DIM);
        #pragma unroll
        for (int c = 0; c < K_CHUNKS; ++c) {
            wA[c] = pA[c * 64 + lane];
            wB[c] = pB[c * 64 + lane];
        }
    }
    const float winA0 = Win[2 * rowA], winA1 = Win[2 * rowA + 1];
    const float winB0 = Win[2 * rowB], winB1 = Win[2 * rowB + 1];

    __syncthreads();

    const float4* rv4 = reinterpret_cast<const float4*>(r_lds);

    for (int t = 0; t < T_STEPS; ++t) {
        if (t > 0) {
            // Wait until every WG has published r(t), then stage rbuf[t&1] -> LDS.
            if (tid < N_WG) {
                while (__hip_atomic_load(&flags[tid], __ATOMIC_ACQUIRE, AGENT) < t)
                    __builtin_amdgcn_s_sleep(1);
            }
            __syncthreads();
            const float* src = rbuf + (size_t)(t & 1) * R_DIM;
            #pragma unroll
            for (int j = 0; j < R_DIM / N_THR; ++j) {
                int i = tid + j * N_THR;   // coalesced, device-coherent loads
                r_lds[i] = __hip_atomic_load(src + i, __ATOMIC_RELAXED, AGENT);
            }
            __syncthreads();

            // pred[t-1] = Wout[0] + Wout[1]*b[t-1] + dot(Wout[2:], r(t))  (WG0 wave0 only,
            // runs concurrently with other waves' matvec; no barrier inside)
            if (wid == 0 && wave == 0) {
                const float* wr = Wout + 2;
                float s = 0.0f;
                #pragma unroll
                for (int c = 0; c < K_CHUNKS; ++c) {
                    int k = c * 256 + lane * 4;
                    float2 wa = *reinterpret_cast<const float2*>(wr + k);
                    float2 wb = *reinterpret_cast<const float2*>(wr + k + 2);
                    float4 rv = rv4[c * 64 + lane];
                    s = fmaf(wa.x, rv.x, s);
                    s = fmaf(wa.y, rv.y, s);
                    s = fmaf(wb.x, rv.z, s);
                    s = fmaf(wb.y, rv.w, s);
                }
                #pragma unroll
                for (int m = 1; m < 64; m <<= 1) s += __shfl_xor(s, m);
                if (lane == 0)
                    out[t - 1] = s + fmaf(Wout[1], b_lds[t - 1], Wout[0]);
            }
        }

        // y = W r(t) for this wave's two rows (W in registers, r broadcast from LDS).
        float4 aA = make_float4(0.f, 0.f, 0.f, 0.f);
        float4 aB = make_float4(0.f, 0.f, 0.f, 0.f);
        #pragma unroll
        for (int c = 0; c < K_CHUNKS; ++c) {
            float4 rv = rv4[c * 64 + lane];
            aA.x = fmaf(wA[c].x, rv.x, aA.x);
            aA.y = fmaf(wA[c].y, rv.y, aA.y);
            aA.z = fmaf(wA[c].z, rv.z, aA.z);
            aA.w = fmaf(wA[c].w, rv.w, aA.w);
            aB.x = fmaf(wB[c].x, rv.x, aB.x);
            aB.y = fmaf(wB[c].y, rv.y, aB.y);
            aB.z = fmaf(wB[c].z, rv.z, aB.z);
            aB.w = fmaf(wB[c].w, rv.w, aB.w);
        }
        float sA = (aA.x + aA.y) + (aA.z + aA.w);
        float sB = (aB.x + aB.y) + (aB.z + aB.w);
        #pragma unroll
        for (int m = 1; m < 64; m <<= 1) {
            sA += __shfl_xor(sA, m);
            sB += __shfl_xor(sB, m);
        }

        if (lane == 0) {
            float bt = b_lds[t];
            float xA = tanhf(sA + fmaf(winA1, bt, winA0));
            float xB = tanhf(sB + fmaf(winB1, bt, winB0));
            float rnA = 0.5f * (r_lds[rowA] + xA);   // (1-leak)*r + leak*x, leak=0.5
            float rnB = 0.5f * (r_lds[rowB] + xB);
            float* dst = rbuf + (size_t)((t + 1) & 1) * R_DIM;
            __hip_atomic_store(dst + rowA, rnA, __ATOMIC_RELAXED, AGENT);
            __hip_atomic_store(dst + rowB, rnB, __ATOMIC_RELAXED, AGENT);
        }
        __syncthreads();   // drains all waves' vmem stores (vmcnt(0) before s_barrier)
        if (tid == 0)
            __hip_atomic_store(&flags[wid], t + 1, __ATOMIC_RELEASE, AGENT);
    }

    // Epilogue: pred[T-1] needs r(T); only WG0 participates (intra-WG barrier is fine).
    if (wid == 0) {
        if (tid < N_WG) {
            while (__hip_atomic_load(&flags[tid], __ATOMIC_ACQUIRE, AGENT) < T_STEPS)
                __builtin_amdgcn_s_sleep(1);
        }
        __syncthreads();
        const float* src = rbuf + (size_t)(T_STEPS & 1) * R_DIM;
        #pragma unroll
        for (int j = 0; j < R_DIM / N_THR; ++j) {
            int i = tid + j * N_THR;
            r_lds[i] = __hip_atomic_load(src + i, __ATOMIC_RELAXED, AGENT);
        }
        __syncthreads();
        if (wave == 0) {
            const float* wr = Wout + 2;
            float s = 0.0f;
            #pragma unroll
            for (int c = 0; c < K_CHUNKS; ++c) {
                int k = c * 256 + lane * 4;
                float2 wa = *reinterpret_cast<const float2*>(wr + k);
                float2 wb = *reinterpret_cast<const float2*>(wr + k + 2);
                float4 rv = rv4[c * 64 + lane];
                s = fmaf(wa.x, rv.x, s);
                s = fmaf(wa.y, rv.y, s);
                s = fmaf(wb.x, rv.z, s);
                s = fmaf(wb.y, rv.w, s);
            }
            #pragma unroll
            for (int m = 1; m < 64; m <<= 1) s += __shfl_xor(s, m);
            if (lane == 0)
                out[T_STEPS - 1] = s + fmaf(Wout[1], b_lds[T_STEPS - 1], Wout[0]);
        }
    }
}

extern "C" void kernel_launch(void* const* d_in, const int* in_sizes, int n_in,
                              void* d_out, int out_size, void* d_ws, size_t ws_size,
                              hipStream_t stream) {
    (void)in_sizes; (void)n_in; (void)out_size; (void)ws_size;
    const float* batch = (const float*)d_in[0];   // (1024,1,1)
    const float* Win   = (const float*)d_in[1];   // (4096,2) row-major
    const float* W     = (const float*)d_in[2];   // (4096,4096) row-major
    const float* Wout  = (const float*)d_in[3];   // (1,4098)
    float* out  = (float*)d_out;                  // (1024,1)
    float* rbuf = (float*)d_ws;                                   // 2*4096 floats
    int*   flags = (int*)((char*)d_ws + 2 * R_DIM * sizeof(float)); // 256 ints

    // flags must start < 1 every launch (d_ws is not re-poisoned between replays).
    hipMemsetAsync(flags, 0, N_WG * sizeof(int), stream);

    // grid=256 WGs (1 per CU: __launch_bounds__(512,2) caps VGPR at 256 so all 8 waves
    // of a WG fit one CU; grid == CU count => all WGs co-resident for the spin barrier).
    esn_persistent<<<dim3(N_WG), dim3(N_THR), 0, stream>>>(
        batch, Win, W, Wout, out, rbuf, flags);
}

// Round 2
// 23915.694 us; speedup vs baseline: 1.0472x; 1.0472x over previous
//
#include <hip/hip_runtime.h>

// Echo State Network, T=1024 sequential steps of r' = 0.5 r + 0.5 tanh(W r + Win u).
// Strategy: persistent kernel, whole 64 MB W pinned in VGPRs (256 WG x 8 waves x 2 rows,
// 128 VGPR of W per lane). Cross-WG step barrier via device-scope flags in d_ws.
//
// Round-2 changes (vs round-1 @ 25 ms):
//  * VGPR_Count=100 proved W was REMATERIALIZED from cache every step (147 MB FETCH,
//    VALUBusy 2.7%). Two fixes:
//    1) inline fast tanh via v_exp_f32 — the tanhf ocml call was a clobber boundary
//       that made LLVM prefer remat over keeping 128 W regs live across it.
//    2) launder every W component through asm("":"+v") — an asm-defined value cannot
//       be rematerialized from memory, forcing true register residency.
//
// d_ws layout: [0, 32768): float rbuf[2][4096] (double-buffered r)
//              [32768, 33792): int flags[256]  (last published step per WG)

#define T_STEPS 1024
#define R_DIM   4096
#define N_WG    256
#define N_THR   512
#define ROWS_PER_WG 16
#define K_CHUNKS 16          // R_DIM / (64 lanes * 4 floats)

#define AGENT __HIP_MEMORY_SCOPE_AGENT

__device__ __forceinline__ float fast_tanh(float x) {
    // tanh(x) = sign(x) * (1 - e) / (1 + e), e = exp(-2|x|).  v_exp_f32 inline, no call.
    float ax = fabsf(x);
    float e  = __expf(-2.0f * ax);
    float t  = (1.0f - e) / (1.0f + e);
    return copysignf(t, x);
}

__global__ __launch_bounds__(N_THR, 2)
void esn_persistent(const float* __restrict__ batch,
                    const float* __restrict__ Win,
                    const float* __restrict__ W,
                    const float* __restrict__ Wout,
                    float* __restrict__ out,
                    float* __restrict__ rbuf,
                    int*   __restrict__ flags)
{
    __shared__ __align__(16) float r_lds[R_DIM];   // current r(t), broadcast to all waves
    __shared__ float b_lds[T_STEPS];               // input sequence

    const int tid  = threadIdx.x;
    const int wid  = blockIdx.x;
    const int wave = tid >> 6;
    const int lane = tid & 63;
    const int r0   = wid * ROWS_PER_WG;
    const int rowA = r0 + wave * 2;                // this wave's two W rows
    const int rowB = rowA + 1;

    for (int i = tid; i < R_DIM; i += N_THR) r_lds[i] = 0.0f;   // r(0) = 0
    for (int i = tid; i < T_STEPS; i += N_THR) b_lds[i] = batch[i];

    // Pin W rows in registers: lane holds float4 slice c at k = c*256 + lane*4.
    float4 wA[K_CHUNKS], wB[K_CHUNKS];
    {
        const float4* pA = reinterpret_cast<const float4*>(W + (size_t)rowA * R_DIM);
        const float4* pB = reinterpret_cast<const float4*>(W + (size_t)rowB * R_DIM);
        #pragma unroll
        for (int c = 0; c < K_CHUNKS; ++c) {
            wA[c] = pA[c * 64 + lane];
            wB[c] = pB[c * 64 + lane];
        }
        // Forbid rematerialization: values are now asm-defined, not load-defined.
        #pragma unroll
        for (int c = 0; c < K_CHUNKS; ++c) {
            asm("" : "+v"(wA[c].x), "+v"(wA[c].y), "+v"(wA[c].z), "+v"(wA[c].w),
                     "+v"(wB[c].x), "+v"(wB[c].y), "+v"(wB[c].z), "+v"(wB[c].w));
        }
    }
    const float winA0 = Win[2 * rowA], winA1 = Win[2 * rowA + 1];
    const float winB0 = Win[2 * rowB], winB1 = Win[2 * rowB + 1];

    __syncthreads();

    const float4* rv4 = reinterpret_cast<const float4*>(r_lds);

    for (int t = 0; t < T_STEPS; ++t) {
        if (t > 0) {
            // Wait until every WG has published r(t), then stage rbuf[t&1] -> LDS.
            if (tid < N_WG) {
                while (__hip_atomic_load(&flags[tid], __ATOMIC_ACQUIRE, AGENT) < t)
                    __builtin_amdgcn_s_sleep(1);
            }
            __syncthreads();
            const float* src = rbuf + (size_t)(t & 1) * R_DIM;
            #pragma unroll
            for (int j = 0; j < R_DIM / N_THR; ++j) {
                int i = tid + j * N_THR;   // coalesced, device-coherent loads
                r_lds[i] = __hip_atomic_load(src + i, __ATOMIC_RELAXED, AGENT);
            }
            __syncthreads();

            // pred[t-1] = Wout[0] + Wout[1]*b[t-1] + dot(Wout[2:], r(t))  (WG0 wave0 only,
            // runs concurrently with other waves' matvec; no barrier inside)
            if (wid == 0 && wave == 0) {
                const float* wr = Wout + 2;
                float s = 0.0f;
                #pragma unroll
                for (int c = 0; c < K_CHUNKS; ++c) {
                    int k = c * 256 + lane * 4;
                    float2 wa = *reinterpret_cast<const float2*>(wr + k);
                    float2 wb = *reinterpret_cast<const float2*>(wr + k + 2);
                    float4 rv = rv4[c * 64 + lane];
                    s = fmaf(wa.x, rv.x, s);
                    s = fmaf(wa.y, rv.y, s);
                    s = fmaf(wb.x, rv.z, s);
                    s = fmaf(wb.y, rv.w, s);
                }
                #pragma unroll
                for (int m = 1; m < 64; m <<= 1) s += __shfl_xor(s, m);
                if (lane == 0)
                    out[t - 1] = s + fmaf(Wout[1], b_lds[t - 1], Wout[0]);
            }
        }

        // y = W r(t) for this wave's two rows (W in registers, r broadcast from LDS).
        float4 aA = make_float4(0.f, 0.f, 0.f, 0.f);
        float4 aB = make_float4(0.f, 0.f, 0.f, 0.f);
        #pragma unroll
        for (int c = 0; c < K_CHUNKS; ++c) {
            float4 rv = rv4[c * 64 + lane];
            aA.x = fmaf(wA[c].x, rv.x, aA.x);
            aA.y = fmaf(wA[c].y, rv.y, aA.y);
            aA.z = fmaf(wA[c].z, rv.z, aA.z);
            aA.w = fmaf(wA[c].w, rv.w, aA.w);
            aB.x = fmaf(wB[c].x, rv.x, aB.x);
            aB.y = fmaf(wB[c].y, rv.y, aB.y);
            aB.z = fmaf(wB[c].z, rv.z, aB.z);
            aB.w = fmaf(wB[c].w, rv.w, aB.w);
        }
        float sA = (aA.x + aA.y) + (aA.z + aA.w);
        float sB = (aB.x + aB.y) + (aB.z + aB.w);
        #pragma unroll
        for (int m = 1; m < 64; m <<= 1) {
            sA += __shfl_xor(sA, m);
            sB += __shfl_xor(sB, m);
        }

        if (lane == 0) {
            float bt = b_lds[t];
            float xA = fast_tanh(sA + fmaf(winA1, bt, winA0));
            float xB = fast_tanh(sB + fmaf(winB1, bt, winB0));
            float rnA = 0.5f * (r_lds[rowA] + xA);   // (1-leak)*r + leak*x, leak=0.5
            float rnB = 0.5f * (r_lds[rowB] + xB);
            float* dst = rbuf + (size_t)((t + 1) & 1) * R_DIM;
            __hip_atomic_store(dst + rowA, rnA, __ATOMIC_RELAXED, AGENT);
            __hip_atomic_store(dst + rowB, rnB, __ATOMIC_RELAXED, AGENT);
        }
        __syncthreads();   // drains all waves' vmem stores (vmcnt(0) before s_barrier)
        if (tid == 0)
            __hip_atomic_store(&flags[wid], t + 1, __ATOMIC_RELEASE, AGENT);
    }

    // Epilogue: pred[T-1] needs r(T); only WG0 participates (intra-WG barrier is fine).
    if (wid == 0) {
        if (tid < N_WG) {
            while (__hip_atomic_load(&flags[tid], __ATOMIC_ACQUIRE, AGENT) < T_STEPS)
                __builtin_amdgcn_s_sleep(1);
        }
        __syncthreads();
        const float* src = rbuf + (size_t)(T_STEPS & 1) * R_DIM;
        #pragma unroll
        for (int j = 0; j < R_DIM / N_THR; ++j) {
            int i = tid + j * N_THR;
            r_lds[i] = __hip_atomic_load(src + i, __ATOMIC_RELAXED, AGENT);
        }
        __syncthreads();
        if (wave == 0) {
            const float* wr = Wout + 2;
            float s = 0.0f;
            #pragma unroll
            for (int c = 0; c < K_CHUNKS; ++c) {
                int k = c * 256 + lane * 4;
                float2 wa = *reinterpret_cast<const float2*>(wr + k);
                float2 wb = *reinterpret_cast<const float2*>(wr + k + 2);
                float4 rv = rv4[c * 64 + lane];
                s = fmaf(wa.x, rv.x, s);
                s = fmaf(wa.y, rv.y, s);
                s = fmaf(wb.x, rv.z, s);
                s = fmaf(wb.y, rv.w, s);
            }
            #pragma unroll
            for (int m = 1; m < 64; m <<= 1) s += __shfl_xor(s, m);
            if (lane == 0)
                out[T_STEPS - 1] = s + fmaf(Wout[1], b_lds[T_STEPS - 1], Wout[0]);
        }
    }
}

extern "C" void kernel_launch(void* const* d_in, const int* in_sizes, int n_in,
                              void* d_out, int out_size, void* d_ws, size_t ws_size,
                              hipStream_t stream) {
    (void)in_sizes; (void)n_in; (void)out_size; (void)ws_size;
    const float* batch = (const float*)d_in[0];   // (1024,1,1)
    const float* Win   = (const float*)d_in[1];   // (4096,2) row-major
    const float* W     = (const float*)d_in[2];   // (4096,4096) row-major
    const float* Wout  = (const float*)d_in[3];   // (1,4098)
    float* out  = (float*)d_out;                  // (1024,1)
    float* rbuf = (float*)d_ws;                                   // 2*4096 floats
    int*   flags = (int*)((char*)d_ws + 2 * R_DIM * sizeof(float)); // 256 ints

    // flags must start < 1 every launch (d_ws is not re-poisoned between replays).
    hipMemsetAsync(flags, 0, N_WG * sizeof(int), stream);

    // grid=256 WGs (1 per CU: 8 waves of 512 thr co-resident; grid == CU count =>
    // all WGs co-resident for the spin barrier).
    esn_persistent<<<dim3(N_WG), dim3(N_THR), 0, stream>>>(
        batch, Win, W, Wout, out, rbuf, flags);
}